// Round 4
// baseline (580.327 us; speedup 1.0000x reference)
//
#include <hip/hip_runtime.h>
#include <hip/hip_bf16.h>
#include <math.h>

#define B_ROWS 16384
#define D_DIM  4096
#define E_EXP  64
#define NW     8                 // waves per block = intra-block K splits
#define DK     32                // staged k per chunk
#define KSLICE (D_DIM / NW)      // 512
#define EPSF   1e-12f

__device__ __forceinline__ float wave_sum(float v) {
#pragma unroll
  for (int m = 32; m > 0; m >>= 1) v += __shfl_xor(v, m, 64);
  return v;
}
__device__ __forceinline__ float wave_max(float v) {
#pragma unroll
  for (int m = 32; m > 0; m >>= 1) v = fmaxf(v, __shfl_xor(v, m, 64));
  return v;
}

// ---------- transpose W[64][4096] -> Wt[4096][64] (enables s_load_dwordx16 of W rows)
__global__ void k_transpose(const float* __restrict__ W, float* __restrict__ Wt) {
  int idx = blockIdx.x * blockDim.x + threadIdx.x;   // grid 1024*256 = 262144
  int e = idx & 63, d = idx >> 6;
  Wt[idx] = W[e * D_DIM + d];
}

// ---------- detect prev_mask upload layout: flag 0 = uint8 bool, 1 = int32, 2 = float32
__global__ void k_detect(const int* __restrict__ pm, int* __restrict__ flag) {
  __shared__ int notI, notF;
  if (threadIdx.x == 0) { notI = 0; notF = 0; }
  __syncthreads();
  for (int i = threadIdx.x; i < 1024; i += blockDim.x) {
    int v = pm[i];
    if (v != 0 && v != 1) atomicOr(&notI, 1);
    float f = __int_as_float(v);
    if (f != 0.0f && f != 1.0f) atomicOr(&notF, 1);
  }
  __syncthreads();
  if (threadIdx.x == 0) *flag = notI ? (notF ? 0 : 2) : 1;
}

// ---------- K1: fp32 GEMM (scalar-operand FMA) + bias + softmax + col-sum partials
// block = 512 thr = 8 waves; wave w handles K slice [w*512, (w+1)*512); lane = row.
__global__ __launch_bounds__(512, 2) void k_gemm_softmax(
    const float* __restrict__ x, const float* __restrict__ Wt,
    const float* __restrict__ bias, float* __restrict__ P,
    double* __restrict__ cs0)
{
  __shared__ float  Xs[NW][64][DK];   // 64 KB, per-wave private x staging
  __shared__ float  Pr[64][65];       // logit reduce + softmax (pad 65: conflict-free)
  __shared__ double csD[NW][64];      // col-sum partials

  const int w    = __builtin_amdgcn_readfirstlane((int)(threadIdx.x >> 6));
  const int lane = (int)(threadIdx.x & 63);
  const int row0 = blockIdx.x * 64;
  const int k0   = w * KSLICE;

  float acc[E_EXP];
#pragma unroll
  for (int e = 0; e < E_EXP; e++) acc[e] = 0.f;

  const int lm8 = lane & 7;
  const int ld8 = lane >> 3;
  const int cg_lane = lm8 ^ ld8;   // data granule this lane fetches (XOR swizzle, see read side)
  const float* gsrc = x + (size_t)(row0 + ld8) * D_DIM + k0 + cg_lane * 4;
  float* lds_dst = &Xs[w][ld8][lm8 * 4];

  for (int kc = 0; kc < KSLICE; kc += DK) {
    // stage 64 rows x 32 cols, coalesced (each instr: 8 rows x 128B contiguous, permuted in-row)
    float4 v[8];
#pragma unroll
    for (int i = 0; i < 8; i++)
      v[i] = *(const float4*)(gsrc + (size_t)i * 8 * D_DIM + kc);
#pragma unroll
    for (int i = 0; i < 8; i++)
      *(float4*)(lds_dst + i * 8 * DK) = v[i];
    // wave-private buffer: no barrier needed; compiler inserts lgkmcnt ordering.

    const float* wkbase = Wt + (size_t)(k0 + kc) * E_EXP;
#pragma unroll 2
    for (int cg = 0; cg < 8; cg++) {
      // row r's data-granule cg sits at phys granule cg ^ (r&7)
      const float4 xv = *(const float4*)&Xs[w][lane][(cg ^ (lane & 7)) * 4];
#pragma unroll
      for (int cc = 0; cc < 4; cc++) {
        const float xs = ((const float*)&xv)[cc];
        const float* wk = wkbase + (cg * 4 + cc) * E_EXP;   // wave-uniform -> s_load
#pragma unroll
        for (int e = 0; e < E_EXP; e++)
          acc[e] = fmaf(wk[e], xs, acc[e]);
      }
    }
  }

  // reduce 8 K-slice partials into Pr[row][e] (deterministic order)
  for (int t = 0; t < NW; t++) {
    if (w == t) {
      if (t == 0) {
#pragma unroll
        for (int e = 0; e < E_EXP; e++) Pr[lane][e] = acc[e];
      } else {
#pragma unroll
        for (int e = 0; e < E_EXP; e++) Pr[lane][e] += acc[e];
      }
    }
    __syncthreads();
  }

  // softmax: wave w handles rows w*8 .. w*8+7; lane = expert
  const float bl = bias[lane];
  float cspart = 0.f;
#pragma unroll
  for (int rr = 0; rr < 8; rr++) {
    int r = w * 8 + rr;
    float lv = Pr[r][lane] + bl;
    float mx = wave_max(lv);
    float p  = expf(lv - mx);
    float s  = wave_sum(p);
    p = p / s;
    P[(size_t)(row0 + r) * E_EXP + lane] = p;
    cspart += p;
  }
  csD[w][lane] = (double)cspart;
  __syncthreads();
  if (w == 0) {
    double t = 0.0;
#pragma unroll
    for (int i = 0; i < NW; i++) t += csD[i][lane];
    atomicAdd(&cs0[lane], t);
  }
}

// ---------- K2: one Sinkhorn iteration (col-normalize via csIn, scale, row-normalize),
// accumulates col sums of the result into csOut (fp64, order-insensitive).
__global__ __launch_bounds__(256, 4) void k_sinkhorn(
    float* __restrict__ P, const double* __restrict__ csIn,
    double* __restrict__ csOut)
{
  __shared__ double csB[4][64];
  const int w = (int)(threadIdx.x >> 6), lane = (int)(threadIdx.x & 63);
  const float csf   = fmaxf((float)csIn[lane], EPSF);
  const float scale = (float)E_EXP / (float)B_ROWS;
  float cspart = 0.f;
  for (int r = blockIdx.x * 4 + w; r < B_ROWS; r += gridDim.x * 4) {
    float p = P[(size_t)r * 64 + lane];
    p = p / csf;
    p = p * scale;
    float rs = wave_sum(p);
    p = p / fmaxf(rs, EPSF);
    P[(size_t)r * 64 + lane] = p;
    cspart += p;
  }
  csB[w][lane] = (double)cspart;
  __syncthreads();
  if (w == 0) {
    double t = csB[0][lane] + csB[1][lane] + csB[2][lane] + csB[3][lane];
    atomicAdd(&csOut[lane], t);
  }
}

// ---------- K3: Sinkhorn iter 3 + hysteresis + inhibit + renorms + top-k mask
__global__ __launch_bounds__(256, 4) void k_final(
    const float* __restrict__ P, const double* __restrict__ cs2,
    const void* __restrict__ pmv, const int* __restrict__ flag,
    const float* __restrict__ inhibit, const int* __restrict__ kinp,
    float* __restrict__ outP, float* __restrict__ outM)
{
  const int w = (int)(threadIdx.x >> 6), lane = (int)(threadIdx.x & 63);
  const int mode = *flag;
  int kk = *kinp;
  if (kk < 0 || kk > 64) {            // tolerate k uploaded as float
    float kf = __int_as_float(kk);
    kk = (int)kf;
  }
  if (kk < 0) kk = 0;
  if (kk > 64) kk = 64;

  const float csf   = fmaxf((float)cs2[lane], EPSF);
  const float scale = (float)E_EXP / (float)B_ROWS;
  const float inh   = inhibit[lane];

  for (int r = blockIdx.x * 4 + w; r < B_ROWS; r += gridDim.x * 4) {
    float p = P[(size_t)r * 64 + lane];
    p = p / csf;
    p = p * scale;
    float rs = wave_sum(p);
    p = p / fmaxf(rs, EPSF);

    float prev;
    if (mode == 1)      prev = (((const int*)pmv)[(size_t)r * 64 + lane] != 0) ? 1.f : 0.f;
    else if (mode == 0) prev = (((const unsigned char*)pmv)[(size_t)r * 64 + lane] != 0) ? 1.f : 0.f;
    else                prev = (((const float*)pmv)[(size_t)r * 64 + lane] != 0.f) ? 1.f : 0.f;

    float pden = fmaxf(wave_sum(prev), 1.0f);
    p = 0.5f * p + 0.5f * (prev / pden);
    float rs2 = wave_sum(p);
    p = p / fmaxf(rs2, EPSF);
    p = p * inh;
    float rs3 = wave_sum(p);
    p = p / fmaxf(rs3, EPSF);
    outP[(size_t)r * 64 + lane] = p;

    // top-k (tie -> lower index, matching stable top_k)
    int sel = 0;
    for (int t = 0; t < kk; t++) {
      float cv = sel ? -INFINITY : p;
      int ci = lane;
#pragma unroll
      for (int m = 32; m > 0; m >>= 1) {
        float ov = __shfl_xor(cv, m, 64);
        int   oi = __shfl_xor(ci, m, 64);
        if (ov > cv || (ov == cv && oi < ci)) { cv = ov; ci = oi; }
      }
      if (lane == ci) sel = 1;
    }
    outM[(size_t)r * 64 + lane] = sel ? 1.f : 0.f;
  }
}

extern "C" void kernel_launch(void* const* d_in, const int* in_sizes, int n_in,
                              void* d_out, int out_size, void* d_ws, size_t ws_size,
                              hipStream_t stream)
{
  (void)in_sizes; (void)n_in; (void)out_size; (void)ws_size;
  const float* x   = (const float*)d_in[0];
  const float* W   = (const float*)d_in[1];
  const float* b   = (const float*)d_in[2];
  const void*  pm  = d_in[3];
  const float* inh = (const float*)d_in[4];
  const int*   kin = (const int*)d_in[5];

  char* ws = (char*)d_ws;
  float*  P    = (float*)ws;                               // 4 MB
  float*  Wt   = (float*)(ws + (size_t)4 * 1024 * 1024);   // 1 MB
  double* cs0  = (double*)(ws + (size_t)5 * 1024 * 1024);  // 3*64 doubles + flag
  double* cs1  = cs0 + 64;
  double* cs2  = cs1 + 64;
  int*    flag = (int*)(cs2 + 64);

  hipMemsetAsync(cs0, 0, 3 * 64 * sizeof(double) + sizeof(int), stream);
  k_transpose<<<1024, 256, 0, stream>>>(W, Wt);
  k_detect<<<1, 256, 0, stream>>>((const int*)pm, flag);
  k_gemm_softmax<<<256, 512, 0, stream>>>(x, Wt, b, P, cs0);
  k_sinkhorn<<<512, 256, 0, stream>>>(P, cs0, cs1);
  k_sinkhorn<<<512, 256, 0, stream>>>(P, cs1, cs2);

  float* outP = (float*)d_out;
  float* outM = outP + (size_t)B_ROWS * E_EXP;
  k_final<<<512, 256, 0, stream>>>(P, cs2, pm, flag, inh, kin, outP, outM);
}